// Round 5
// baseline (50.506 us; speedup 1.0000x reference)
//
#include <hip/hip_runtime.h>
#include <hip/hip_bf16.h>

// Problem constants (from reference setup_inputs: b=4, s=4096, d=2048, CAPACITY=0.5)
#define BATCH 4
#define SEQ   4096
#define DMODEL 2048
#define KSEL  2048   // max(1, int(SEQ*0.5))

// ---------------------------------------------------------------------------
// Kernel 1: logits = x @ gate_w (fp64 accumulate), weights = sigmoid(logits)
// 1024 persistent blocks x 256 threads; grid-stride over 2-row wave tasks
// (each wave executes exactly 2 passes). gate_w (8 float4/lane) loaded once
// per wave and reused across 4 rows. Per row: 8 float4 x-loads then 32 fp64
// FMAs in 4 independent chains. Per-row summation order is IDENTICAL to the
// R2/R4 kernels -> bit-identical logits (top-k ranking stability).
// ---------------------------------------------------------------------------
__global__ __launch_bounds__(256) void logits_kernel(
    const float* __restrict__ x,
    const float* __restrict__ gate_w,
    float* __restrict__ logits,     // [BATCH*SEQ] in workspace
    float* __restrict__ weights)    // [BATCH*SEQ] -> d_out + BATCH*SEQ
{
    const int wave   = threadIdx.x >> 6;
    const int lane   = threadIdx.x & 63;
    const int nwaves = gridDim.x * 4;                // 4096

    const float4* wr = reinterpret_cast<const float4*>(gate_w);
    float4 wv[8];
#pragma unroll
    for (int t = 0; t < 8; ++t) wv[t] = wr[t * 64 + lane];

    for (int wid = blockIdx.x * 4 + wave; wid < (BATCH * SEQ) / 2; wid += nwaves) {
        const int row0 = wid * 2;                    // 2 consecutive rows

        double rsum[2];
#pragma unroll
        for (int r = 0; r < 2; ++r) {
            const float4* xr =
                reinterpret_cast<const float4*>(x + (size_t)(row0 + r) * DMODEL);
            float4 xv[8];
#pragma unroll
            for (int t = 0; t < 8; ++t) xv[t] = xr[t * 64 + lane];

            double a0 = 0.0, a1 = 0.0, a2 = 0.0, a3 = 0.0;
#pragma unroll
            for (int t = 0; t < 8; ++t) {
                a0 += (double)xv[t].x * (double)wv[t].x;
                a1 += (double)xv[t].y * (double)wv[t].y;
                a2 += (double)xv[t].z * (double)wv[t].z;
                a3 += (double)xv[t].w * (double)wv[t].w;
            }
            rsum[r] = (a0 + a1) + (a2 + a3);
        }

        // 64-lane reduction, 2 independent fp64 chains interleaved
#pragma unroll
        for (int off = 32; off > 0; off >>= 1) {
            rsum[0] += __shfl_down(rsum[0], off, 64);
            rsum[1] += __shfl_down(rsum[1], off, 64);
        }

        if (lane == 0) {
#pragma unroll
            for (int r = 0; r < 2; ++r) {
                float l = (float)rsum[r];
                logits[row0 + r]  = l;
                weights[row0 + r] = 1.0f / (1.0f + expf(-l));
            }
        }
    }
}

// ---------------------------------------------------------------------------
// Kernel 2 (merged select + finalize), 1025 blocks x 256 threads:
//   blocks 0..1023 : top-K mask, 16 output elements per block
//                    (chunk = blk>>2 of 64 elems, quarter = blk&3)
//   block  1024    : aux_loss = unbiased variance of weights
// Mask blocks: full 4096-float row staged in LDS. Thread (e = tid&15,
// slice = tid>>4) compares its element against 1/16 of the row (256 floats).
// Slice-rotated traversal t=(tt+slice)&63 puts the 4 concurrent slice
// broadcasts of each wave on disjoint bank groups {0,4,8,12} (s vs s+8 is
// 2-way = free). 4 blocks/CU -> VALU work spread across all CUs.
// Tie-break matches jax.lax.top_k (lower index wins) via rare-path recount.
// ---------------------------------------------------------------------------
__global__ __launch_bounds__(256) void select_finalize_kernel(
    const float* __restrict__ logits,
    const float* __restrict__ weights,
    float* __restrict__ mask,       // -> d_out + 0
    float* __restrict__ aux)        // -> d_out + 2*BATCH*SEQ
{
    if (blockIdx.x == 1024) {
        // ---- variance block (256 threads, fp64) ----
        const int n = BATCH * SEQ;
        double s = 0.0, s2 = 0.0;
        for (int i = threadIdx.x; i < n; i += 256) {
            double w = (double)weights[i];
            s  += w;
            s2 += w * w;
        }
#pragma unroll
        for (int off = 32; off > 0; off >>= 1) {
            s  += __shfl_down(s,  off, 64);
            s2 += __shfl_down(s2, off, 64);
        }
        __shared__ double sh[8];
        const int wid  = threadIdx.x >> 6;
        const int lane = threadIdx.x & 63;
        if (lane == 0) { sh[wid] = s; sh[wid + 4] = s2; }
        __syncthreads();
        if (threadIdx.x == 0) {
            double S  = sh[0] + sh[1] + sh[2] + sh[3];
            double S2 = sh[4] + sh[5] + sh[6] + sh[7];
            double mean = S / n;
            double var  = (S2 - (double)n * mean * mean) / (double)(n - 1);
            *aux = (float)var;
        }
        return;
    }

    const int blk   = blockIdx.x;
    const int chunk = blk >> 2;          // 0..255 : 64-element chunk id
    const int b     = chunk >> 6;        // batch
    const int q     = blk & 3;           // quarter of the chunk

    __shared__ float L[SEQ];             // 16 KiB row
    __shared__ int sh_gt[16][17];        // [e][slice], stride 17 -> conflict-free
    __shared__ int sh_eq[16][17];

    const float* row = logits + b * SEQ;
    for (int i = threadIdx.x; i < SEQ / 4; i += 256)
        reinterpret_cast<float4*>(L)[i] =
            reinterpret_cast<const float4*>(row)[i];
    __syncthreads();

    const int e     = threadIdx.x & 15;
    const int slice = threadIdx.x >> 4;  // 0..15
    const int i     = (chunk & 63) * 64 + q * 16 + e;
    const float v   = L[i];

    int gt = 0, eq = 0;
    const int j0 = slice * (SEQ / 16);   // 256-float slice
#pragma unroll 4
    for (int tt = 0; tt < 64; ++tt) {
        const int t = (tt + slice) & 63;
        float4 qd = *reinterpret_cast<const float4*>(&L[j0 + t * 4]);
        gt += (qd.x > v) + (qd.y > v) + (qd.z > v) + (qd.w > v);
        eq += (qd.x == v) + (qd.y == v) + (qd.z == v) + (qd.w == v);
    }
    sh_gt[e][slice] = gt;
    sh_eq[e][slice] = eq;
    __syncthreads();

    if (slice == 0) {                    // threads 0..15
        int GT = 0, EQ = 0;
#pragma unroll
        for (int s = 0; s < 16; ++s) { GT += sh_gt[e][s]; EQ += sh_eq[e][s]; }
        float m;
        if (GT >= KSEL) {
            m = 0.0f;
        } else if (EQ == 1) {
            m = 1.0f;                    // unique value, strictly inside top-K
        } else {
            // Rare tie path: jax top_k takes ties in increasing index order.
            int lower = 0;
            for (int j = 0; j < i; ++j) lower += (L[j] == v);
            m = (GT + lower < KSEL) ? 1.0f : 0.0f;
        }
        mask[b * SEQ + i] = m;
    }
}

extern "C" void kernel_launch(void* const* d_in, const int* in_sizes, int n_in,
                              void* d_out, int out_size, void* d_ws, size_t ws_size,
                              hipStream_t stream) {
    const float* x      = (const float*)d_in[0];   // [4,4096,2048] f32
    const float* gate_w = (const float*)d_in[1];   // [2048] f32

    float* out     = (float*)d_out;
    float* mask    = out;                          // [4,4096,1]
    float* weights = out + BATCH * SEQ;            // [4,4096,1]
    float* aux     = out + 2 * BATCH * SEQ;        // [1]

    float* logits = (float*)d_ws;                  // [4*4096] scratch

    // K1: logits + weights (1024 persistent blocks, 2 passes x 2 rows/wave)
    logits_kernel<<<dim3(1024), dim3(256), 0, stream>>>(
        x, gate_w, logits, weights);

    // K2: top-K mask (1024 blocks x 16 elems) + variance (1 block)
    select_finalize_kernel<<<dim3(1025), dim3(256), 0, stream>>>(
        logits, weights, mask, aux);
}

// Round 7
// 40.337 us; speedup vs baseline: 1.2521x; 1.2521x over previous
//
#include <hip/hip_runtime.h>
#include <hip/hip_bf16.h>

// Problem constants (from reference setup_inputs: b=4, s=4096, d=2048, CAPACITY=0.5)
#define BATCH 4
#define SEQ   4096
#define DMODEL 2048
#define KSEL  2048   // max(1, int(SEQ*0.5))

// Native clang vector type: __builtin_nontemporal_load requires a pointer to
// scalar/vector-of-scalar, not HIP's HIP_vector_type class.
typedef float f32x4 __attribute__((ext_vector_type(4)));

// ---------------------------------------------------------------------------
// Kernel 1: logits = x @ gate_w (fp64 accumulate), weights = sigmoid(logits)
// 2048 blocks x 256 threads; each 64-lane wave owns 2 consecutive rows.
// ALL 16 x float4 loads (both rows) are issued non-temporally BEFORE any
// FMA -> 256 B/lane in flight per wave (R5 showed K1 is MLP-sensitive).
// gate_w (8 float4/lane) loaded once per wave. Per-row FMA order identical
// to R2/R4 -> bit-identical logits (top-k ranking stability).
// ---------------------------------------------------------------------------
__global__ __launch_bounds__(256) void logits_kernel(
    const float* __restrict__ x,
    const float* __restrict__ gate_w,
    float* __restrict__ logits,     // [BATCH*SEQ] in workspace
    float* __restrict__ weights)    // [BATCH*SEQ] -> d_out + BATCH*SEQ
{
    const int wave = threadIdx.x >> 6;
    const int lane = threadIdx.x & 63;
    const int wid  = blockIdx.x * 4 + wave;          // 0 .. 8191
    const int row0 = wid * 2;                        // 2 consecutive rows

    const f32x4* wr  = reinterpret_cast<const f32x4*>(gate_w);
    const f32x4* xr0 = reinterpret_cast<const f32x4*>(x + (size_t)row0 * DMODEL);
    const f32x4* xr1 = reinterpret_cast<const f32x4*>(x + (size_t)(row0 + 1) * DMODEL);

    // Issue all 16 streaming loads first (non-temporal: x is read exactly once).
    f32x4 xv0[8], xv1[8];
#pragma unroll
    for (int t = 0; t < 8; ++t) xv0[t] = __builtin_nontemporal_load(&xr0[t * 64 + lane]);
#pragma unroll
    for (int t = 0; t < 8; ++t) xv1[t] = __builtin_nontemporal_load(&xr1[t * 64 + lane]);

    f32x4 wv[8];
#pragma unroll
    for (int t = 0; t < 8; ++t) wv[t] = wr[t * 64 + lane];

    // Row 0 (summation order identical to previous rounds)
    double a0 = 0.0, a1 = 0.0, a2 = 0.0, a3 = 0.0;
#pragma unroll
    for (int t = 0; t < 8; ++t) {
        a0 += (double)xv0[t].x * (double)wv[t].x;
        a1 += (double)xv0[t].y * (double)wv[t].y;
        a2 += (double)xv0[t].z * (double)wv[t].z;
        a3 += (double)xv0[t].w * (double)wv[t].w;
    }
    double rsum0 = (a0 + a1) + (a2 + a3);

    // Row 1
    double b0 = 0.0, b1 = 0.0, b2 = 0.0, b3 = 0.0;
#pragma unroll
    for (int t = 0; t < 8; ++t) {
        b0 += (double)xv1[t].x * (double)wv[t].x;
        b1 += (double)xv1[t].y * (double)wv[t].y;
        b2 += (double)xv1[t].z * (double)wv[t].z;
        b3 += (double)xv1[t].w * (double)wv[t].w;
    }
    double rsum1 = (b0 + b1) + (b2 + b3);

    // 64-lane reduction, 2 independent fp64 chains interleaved
#pragma unroll
    for (int off = 32; off > 0; off >>= 1) {
        rsum0 += __shfl_down(rsum0, off, 64);
        rsum1 += __shfl_down(rsum1, off, 64);
    }

    if (lane == 0) {
        float l0 = (float)rsum0;
        float l1 = (float)rsum1;
        logits[row0]      = l0;
        logits[row0 + 1]  = l1;
        weights[row0]     = 1.0f / (1.0f + expf(-l0));
        weights[row0 + 1] = 1.0f / (1.0f + expf(-l1));
    }
}

// ---------------------------------------------------------------------------
// Kernel 2 (merged select + finalize), 512 threads/block  [frozen from R4]:
//   blocks 0 .. BATCH*64-1 : top-K mask via exact rank counting
//   block  BATCH*64        : aux_loss = unbiased variance of weights
// Mask blocks: full 4096-float row staged in LDS; thread (e = tid&63,
// slice = tid>>6, 8 slices) compares its element against 1/8 of the row via
// wave-uniform float4 LDS reads (broadcast, conflict-free). Tie-break
// matches jax.lax.top_k (lower index wins) via the rare-path recount.
// ---------------------------------------------------------------------------
__global__ __launch_bounds__(512) void select_finalize_kernel(
    const float* __restrict__ logits,
    const float* __restrict__ weights,
    float* __restrict__ mask,       // -> d_out + 0
    float* __restrict__ aux)        // -> d_out + 2*BATCH*SEQ
{
    if (blockIdx.x == BATCH * 64) {
        // ---- variance block (512 threads, fp64) ----
        const int n = BATCH * SEQ;
        double s = 0.0, s2 = 0.0;
        for (int i = threadIdx.x; i < n; i += 512) {
            double w = (double)weights[i];
            s  += w;
            s2 += w * w;
        }
#pragma unroll
        for (int off = 32; off > 0; off >>= 1) {
            s  += __shfl_down(s,  off, 64);
            s2 += __shfl_down(s2, off, 64);
        }
        __shared__ double sh[16];
        const int wid  = threadIdx.x >> 6;
        const int lane = threadIdx.x & 63;
        if (lane == 0) { sh[wid] = s; sh[wid + 8] = s2; }
        __syncthreads();
        if (threadIdx.x == 0) {
            double S = 0.0, S2 = 0.0;
#pragma unroll
            for (int w = 0; w < 8; ++w) { S += sh[w]; S2 += sh[w + 8]; }
            double mean = S / n;
            double var  = (S2 - (double)n * mean * mean) / (double)(n - 1);
            *aux = (float)var;
        }
        return;
    }

    const int b    = blockIdx.x >> 6;    // batch
    const int eblk = blockIdx.x & 63;    // element chunk (64 elements)

    __shared__ float L[SEQ];
    __shared__ int sh_gt[64][9];         // [e][slice], stride 9 (odd) -> 2-way max
    __shared__ int sh_eq[64][9];

    const float* row = logits + b * SEQ;
    for (int i = threadIdx.x; i < SEQ / 4; i += 512)
        reinterpret_cast<float4*>(L)[i] =
            reinterpret_cast<const float4*>(row)[i];
    __syncthreads();

    const int e     = threadIdx.x & 63;
    const int slice = threadIdx.x >> 6;  // 0..7
    const int i     = eblk * 64 + e;
    const float v   = L[i];

    int gt = 0, eq = 0;
    const int j0 = slice * (SEQ / 8);
#pragma unroll 4
    for (int j = j0; j < j0 + SEQ / 8; j += 4) {
        float4 q = *reinterpret_cast<const float4*>(&L[j]);
        gt += (q.x > v) + (q.y > v) + (q.z > v) + (q.w > v);
        eq += (q.x == v) + (q.y == v) + (q.z == v) + (q.w == v);
    }
    sh_gt[e][slice] = gt;
    sh_eq[e][slice] = eq;
    __syncthreads();

    if (slice == 0) {
        int GT = 0, EQ = 0;
#pragma unroll
        for (int t = 0; t < 8; ++t) { GT += sh_gt[e][t]; EQ += sh_eq[e][t]; }
        float m;
        if (GT >= KSEL) {
            m = 0.0f;
        } else if (EQ == 1) {
            m = 1.0f;                  // unique value, strictly inside top-K
        } else {
            // Rare tie path: jax top_k takes ties in increasing index order.
            int lower = 0;
            for (int j = 0; j < i; ++j) lower += (L[j] == v);
            m = (GT + lower < KSEL) ? 1.0f : 0.0f;
        }
        mask[b * SEQ + i] = m;
    }
}

extern "C" void kernel_launch(void* const* d_in, const int* in_sizes, int n_in,
                              void* d_out, int out_size, void* d_ws, size_t ws_size,
                              hipStream_t stream) {
    const float* x      = (const float*)d_in[0];   // [4,4096,2048] f32
    const float* gate_w = (const float*)d_in[1];   // [2048] f32

    float* out     = (float*)d_out;
    float* mask    = out;                          // [4,4096,1]
    float* weights = out + BATCH * SEQ;            // [4,4096,1]
    float* aux     = out + 2 * BATCH * SEQ;        // [1]

    float* logits = (float*)d_ws;                  // [4*4096] scratch

    // K1: logits + weights  (2048 blocks x 4 waves x 2 rows/wave = 16384 rows)
    logits_kernel<<<dim3(BATCH * SEQ / 8), dim3(256), 0, stream>>>(
        x, gate_w, logits, weights);

    // K2: top-K mask per batch + variance (one extra block)
    select_finalize_kernel<<<dim3(BATCH * 64 + 1), dim3(512), 0, stream>>>(
        logits, weights, mask, aux);
}